// Round 7
// baseline (124.275 us; speedup 1.0000x reference)
//
#include <hip/hip_runtime.h>

#define G_     8
#define D_     144
#define O_     32
#define CIN_   16
#define BATCH_ 8
#define KDIM_  (D_*G_)            // 1152
#define NPIX_  (BATCH_*64*64)     // 32768
#define KC_    (KDIM_/32)         // 36
#define NBLK_  256                // main blocks (128 pixels each)
#define REP_   16                 // DIAGNOSTIC work multiplier (main only)

typedef float  f32x4   __attribute__((ext_vector_type(4)));
typedef short  short8v __attribute__((ext_vector_type(8)));
typedef unsigned short ushort4v __attribute__((ext_vector_type(4)));

// ws layout:
//   [0, 73728)         Bpack: ushort[36][2][64][8]  bf16 B-fragments
//   [73728, 90112)     part:  float[256][64]  (s[32] | q[32]) per main-block
#define PART_OFF  73728

__device__ __forceinline__ unsigned int pack2bf(float a, float b) {
    unsigned int ua = __float_as_uint(a) + 0x8000u;
    unsigned int ub = __float_as_uint(b) + 0x8000u;
    return __builtin_amdgcn_perm(ub, ua, 0x07060302u);   // {hi16(ub),hi16(ua)}
}

// ---------- Wsum -> bf16 B-fragments ----------
__global__ void __launch_bounds__(256)
wsum_kernel(const float* __restrict__ W, unsigned short* __restrict__ Bpack) {
    int t  = blockIdx.x * 256 + threadIdx.x;
    int s  = t & 7;                      // d-split
    int pr = t >> 3;                     // (o, k4)
    int o  = pr / (KDIM_ / 4);
    int k4 = pr - o * (KDIM_ / 4);
    const float4* p = reinterpret_cast<const float4*>(
        W + (size_t)o * (D_ * KDIM_) + (size_t)(s * 18) * KDIM_) + k4;
    float4 a = make_float4(0.f, 0.f, 0.f, 0.f);
#pragma unroll
    for (int dd = 0; dd < 18; ++dd) {
        float4 v = p[dd * (KDIM_ / 4)];
        a.x += v.x; a.y += v.y; a.z += v.z; a.w += v.w;
    }
    a.x += __shfl_xor(a.x, 1); a.y += __shfl_xor(a.y, 1);
    a.z += __shfl_xor(a.z, 1); a.w += __shfl_xor(a.w, 1);
    a.x += __shfl_xor(a.x, 2); a.y += __shfl_xor(a.y, 2);
    a.z += __shfl_xor(a.z, 2); a.w += __shfl_xor(a.w, 2);
    a.x += __shfl_xor(a.x, 4); a.y += __shfl_xor(a.y, 4);
    a.z += __shfl_xor(a.z, 4); a.w += __shfl_xor(a.w, 4);
    if (s == 0) {
        float v[4] = {a.x, a.y, a.z, a.w};
        ushort4v hb;
#pragma unroll
        for (int j = 0; j < 4; ++j) {
            unsigned int u = __float_as_uint(v[j]);
            u += 0x7FFFu + ((u >> 16) & 1u);          // RNE to bf16
            hb[j] = (unsigned short)(u >> 16);
        }
        int k  = k4 * 4;
        int kc = k >> 5;
        int lane_ = (((k >> 3) & 3) << 4) | (o & 15);
        int hh = o >> 4, e = k & 7;
        *reinterpret_cast<ushort4v*>(
            &Bpack[(((kc * 2 + hh) * 64) + lane_) * 8 + e]) = hb;
    }
}

// ---------- fused basis + MFMA GEMM + BN partials (x16 DIAGNOSTIC) ----------
__global__ void __launch_bounds__(512, 2)
main_kernel(const float* __restrict__ x, const unsigned int* __restrict__ Bpack,
            float* __restrict__ out, float* __restrict__ part) {
    constexpr float A_S = 2.1019642153762871f;   // sqrt(log2 e) * 7/4

    __shared__ uint4 Bsh[KC_ * 2 * 64];          // 73728 B

    const uint4* Bg = reinterpret_cast<const uint4*>(Bpack);
#pragma unroll
    for (int i = 0; i < 9; ++i) {
        int idx = threadIdx.x + i * 512;
        Bsh[idx] = Bg[idx];
    }

    int tid  = threadIdx.x;
    int l    = tid & 63;
    int wv   = tid >> 6;
    int m    = l & 15;
    int hi   = l >> 4;
    int pixbase = blockIdx.x * 128 + wv * 16;
    int n    = pixbase + m;
    int b    = n >> 12;
    int y    = (n >> 6) & 63;
    int xc   = n & 63;
    const float* xb = x + ((size_t)b << 16);

    float p[KC_];
#pragma unroll
    for (int kc = 0; kc < KC_; ++kc) {
        int d  = kc * 4 + hi;
        int c  = (d * 57) >> 9;          // d/9
        int r9 = d - c * 9;
        int kh = (r9 * 11) >> 5;         // r9/3
        int kw = r9 - kh * 3;
        int iy = y + kh - 1;
        int ix = xc + kw - 1;
        bool valid = ((unsigned)iy < 64u) & ((unsigned)ix < 64u);
        p[kc] = valid ? xb[(c << 12) + (iy << 6) + ix] : 0.f;
    }
    __syncthreads();                     // B staged

    f32x4 acc0 = {0.f, 0.f, 0.f, 0.f};
    f32x4 acc1 = {0.f, 0.f, 0.f, 0.f};

#pragma unroll 1
    for (int rep = 0; rep < REP_; ++rep) {
        // force re-execution: p[] appears redefined, LDS appears modified
#pragma unroll
        for (int kc = 0; kc < KC_; ++kc) asm volatile("" : "+v"(p[kc]));
        asm volatile("" ::: "memory");

        f32x4 a0 = {0.f, 0.f, 0.f, 0.f};
        f32x4 a1 = {0.f, 0.f, 0.f, 0.f};
#pragma unroll
        for (int kc = 0; kc < KC_; ++kc) {
            float pv = p[kc];
            float e[G_];
#pragma unroll
            for (int g = 0; g < G_; ++g) {
                float gv = -2.0f + (float)g * (4.0f / 7.0f);
                float r  = fmaf(pv, A_S, -gv * A_S);
                e[g] = __builtin_amdgcn_exp2f(-(r * r));
            }
            uint4 au;
            au.x = pack2bf(e[0], e[1]);
            au.y = pack2bf(e[2], e[3]);
            au.z = pack2bf(e[4], e[5]);
            au.w = pack2bf(e[6], e[7]);
            short8v afrag = __builtin_bit_cast(short8v, au);

            short8v b0 = __builtin_bit_cast(short8v, Bsh[(kc * 2 + 0) * 64 + l]);
            short8v b1 = __builtin_bit_cast(short8v, Bsh[(kc * 2 + 1) * 64 + l]);
            a0 = __builtin_amdgcn_mfma_f32_16x16x32_bf16(afrag, b0, a0, 0, 0, 0);
            a1 = __builtin_amdgcn_mfma_f32_16x16x32_bf16(afrag, b1, a1, 0, 0, 0);
        }
        acc0 = a0; acc1 = a1;            // last rep's (identical) value survives
        asm volatile("" :: "v"(a0.x), "v"(a0.y), "v"(a0.z), "v"(a0.w),
                           "v"(a1.x), "v"(a1.y), "v"(a1.z), "v"(a1.w));
    }

    int prp = (pixbase & 4095) + hi * 4;
    float* dst0 = out + (((size_t)(b * O_ + m)) << 12) + prp;
    float* dst1 = out + (((size_t)(b * O_ + m + 16)) << 12) + prp;
    *reinterpret_cast<f32x4*>(dst0) = acc0;
    *reinterpret_cast<f32x4*>(dst1) = acc1;

    float s0 = acc0.x + acc0.y + acc0.z + acc0.w;
    float q0 = acc0.x*acc0.x + acc0.y*acc0.y + acc0.z*acc0.z + acc0.w*acc0.w;
    float s1 = acc1.x + acc1.y + acc1.z + acc1.w;
    float q1 = acc1.x*acc1.x + acc1.y*acc1.y + acc1.z*acc1.z + acc1.w*acc1.w;
    s0 += __shfl_xor(s0, 16); s0 += __shfl_xor(s0, 32);
    q0 += __shfl_xor(q0, 16); q0 += __shfl_xor(q0, 32);
    s1 += __shfl_xor(s1, 16); s1 += __shfl_xor(s1, 32);
    q1 += __shfl_xor(q1, 16); q1 += __shfl_xor(q1, 32);

    float* red = (float*)Bsh;
    __syncthreads();
    if (l < 16) {
        red[wv * 64 +      m] = s0;
        red[wv * 64 + 16 + m] = s1;
        red[wv * 64 + 32 + m] = q0;
        red[wv * 64 + 48 + m] = q1;
    }
    __syncthreads();
    if (tid < 64) {
        float v = 0.f;
#pragma unroll
        for (int w = 0; w < 8; ++w) v += red[w * 64 + tid];
        part[blockIdx.x * 64 + tid] = v;
    }
}

// ---------- BN apply ----------
__global__ void __launch_bounds__(256)
bn_apply(float* __restrict__ out, const float* __restrict__ part,
         const float* __restrict__ gamma, const float* __restrict__ beta) {
    __shared__ float red[256 + 64];
    int tid = threadIdx.x;
    int ch  = tid & 63, grp = tid >> 6;
    float a = 0.f;
#pragma unroll 8
    for (int i = 0; i < 64; ++i)
        a += part[(grp * 64 + i) * 64 + ch];
    red[grp * 64 + ch] = a;
    __syncthreads();
    if (tid < 64)
        red[256 + tid] = red[tid] + red[64 + tid] + red[128 + tid] + red[192 + tid];
    __syncthreads();

    int o = blockIdx.x & 31;
    float S = red[256 + o], Q = red[256 + 32 + o];
    float mean = S * (1.f / (float)NPIX_);
    float var  = Q * (1.f / (float)NPIX_) - mean * mean;
    float rstd = rsqrtf(var + 1e-5f);
    float sc   = gamma[o] * rstd;
    float sh   = beta[o] - mean * sc;

    float4* f4 = reinterpret_cast<float4*>(out) + (size_t)blockIdx.x * 1024;
#pragma unroll
    for (int j = 0; j < 4; ++j) {
        float4 v = f4[tid + j * 256];
        v.x = v.x * sc + sh; v.y = v.y * sc + sh;
        v.z = v.z * sc + sh; v.w = v.w * sc + sh;
        f4[tid + j * 256] = v;
    }
}

extern "C" void kernel_launch(void* const* d_in, const int* in_sizes, int n_in,
                              void* d_out, int out_size, void* d_ws, size_t ws_size,
                              hipStream_t stream) {
    const float* x     = (const float*)d_in[0];
    const float* W     = (const float*)d_in[1];
    const float* gamma = (const float*)d_in[2];
    const float* beta  = (const float*)d_in[3];
    float* out = (float*)d_out;
    unsigned short* Bpack = (unsigned short*)d_ws;
    float* part = (float*)((char*)d_ws + PART_OFF);

    hipLaunchKernelGGL(wsum_kernel, dim3(288), dim3(256), 0, stream, W, Bpack);
    hipLaunchKernelGGL(main_kernel, dim3(NBLK_), dim3(512), 0, stream,
                       x, (const unsigned int*)Bpack, out, part);
    hipLaunchKernelGGL(bn_apply, dim3(256), dim3(256), 0, stream,
                       out, part, gamma, beta);
}

// Round 8
// 28.431 us; speedup vs baseline: 4.3711x; 4.3711x over previous
//
#include <hip/hip_runtime.h>

#define G_     8
#define D_     144
#define O_     32
#define BATCH_ 8
#define KDIM_  (D_*G_)            // 1152
#define NPIX_  (BATCH_*64*64)     // 32768
#define KC_    36                 // K chunks of 32
#define NMAIN_ 512                // main blocks (64 px each)

typedef float  f32x4   __attribute__((ext_vector_type(4)));
typedef short  short8v __attribute__((ext_vector_type(8)));
typedef unsigned short ushort4v __attribute__((ext_vector_type(4)));

// ws layout:
//   [0, 73728)           Bpack: ushort[36][2][64][8]  bf16 B-fragments
//   [73728, 204800)      part:  float[512][64]
//   [204800, 8593424)    Xb:    uint4[524289]  per-input-pixel basis (8 bf16)
//                        slot 524288 = basis(0) for padding redirect
#define PART_OFF 73728
#define XB_OFF   204800
#define XB_CONST 524288

__device__ __forceinline__ unsigned int pack2bf(float a, float b) {
    unsigned int ua = __float_as_uint(a) + 0x8000u;
    unsigned int ub = __float_as_uint(b) + 0x8000u;
    return __builtin_amdgcn_perm(ub, ua, 0x07060302u);   // {hi16(ub),hi16(ua)}
}

__device__ __forceinline__ uint4 basis8(float pv) {
    constexpr float A_S = 2.1019642153762871f;   // sqrt(log2 e) * 7/4
    float e[G_];
#pragma unroll
    for (int g = 0; g < G_; ++g) {
        float gv = -2.0f + (float)g * (4.0f / 7.0f);
        float r  = fmaf(pv, A_S, -gv * A_S);
        e[g] = __builtin_amdgcn_exp2f(-(r * r));
    }
    uint4 au;
    au.x = pack2bf(e[0], e[1]);
    au.y = pack2bf(e[2], e[3]);
    au.z = pack2bf(e[4], e[5]);
    au.w = pack2bf(e[6], e[7]);
    return au;
}

// ---------- prep: blocks 0-287 Wsum->B-frags; blocks 288-2335 basis ----------
__global__ void __launch_bounds__(256)
prep_kernel(const float* __restrict__ W, const float* __restrict__ x,
            unsigned short* __restrict__ Bpack, uint4* __restrict__ Xb) {
    int bid = blockIdx.x;
    if (bid < 288) {
        int t  = bid * 256 + threadIdx.x;
        int s  = t & 7;                      // d-split
        int pr = t >> 3;                     // (o, k4)
        int o  = pr / (KDIM_ / 4);
        int k4 = pr - o * (KDIM_ / 4);
        const float4* p = reinterpret_cast<const float4*>(
            W + (size_t)o * (D_ * KDIM_) + (size_t)(s * 18) * KDIM_) + k4;
        float4 a = make_float4(0.f, 0.f, 0.f, 0.f);
#pragma unroll
        for (int dd = 0; dd < 18; ++dd) {
            float4 v = p[dd * (KDIM_ / 4)];
            a.x += v.x; a.y += v.y; a.z += v.z; a.w += v.w;
        }
        a.x += __shfl_xor(a.x, 1); a.y += __shfl_xor(a.y, 1);
        a.z += __shfl_xor(a.z, 1); a.w += __shfl_xor(a.w, 1);
        a.x += __shfl_xor(a.x, 2); a.y += __shfl_xor(a.y, 2);
        a.z += __shfl_xor(a.z, 2); a.w += __shfl_xor(a.w, 2);
        a.x += __shfl_xor(a.x, 4); a.y += __shfl_xor(a.y, 4);
        a.z += __shfl_xor(a.z, 4); a.w += __shfl_xor(a.w, 4);
        if (s == 0) {
            float v[4] = {a.x, a.y, a.z, a.w};
            ushort4v hb;
#pragma unroll
            for (int j = 0; j < 4; ++j) {
                unsigned int u = __float_as_uint(v[j]);
                u += 0x7FFFu + ((u >> 16) & 1u);          // RNE to bf16
                hb[j] = (unsigned short)(u >> 16);
            }
            int k  = k4 * 4;
            int kc = k >> 5;
            int lane_ = (((k >> 3) & 3) << 4) | (o & 15);
            int hh = o >> 4, e = k & 7;
            *reinterpret_cast<ushort4v*>(
                &Bpack[(((kc * 2 + hh) * 64) + lane_) * 8 + e]) = hb;
        }
    } else {
        int pi = (bid - 288) * 256 + threadIdx.x;    // 524288 input pixels
        Xb[pi] = basis8(x[pi]);
        if (pi == 0) Xb[XB_CONST] = basis8(0.0f);    // padding constant
    }
}

// ---------- main: MFMA GEMM, A-frags loaded from Xb ----------
__global__ void __launch_bounds__(256, 2)
main_kernel(const uint4* __restrict__ Xb, const uint4* __restrict__ Bpackv,
            float* __restrict__ out, float* __restrict__ part) {
    __shared__ uint4 Bsh[KC_ * 2 * 64];          // 73728 B; reused for reduce

#pragma unroll
    for (int i = 0; i < 18; ++i) {
        int idx = threadIdx.x + i * 256;
        Bsh[idx] = Bpackv[idx];
    }

    int tid  = threadIdx.x;
    int l    = tid & 63;
    int wv   = tid >> 6;         // 0..3
    int m    = l & 15;
    int hi   = l >> 4;
    int pixbase = blockIdx.x * 64 + wv * 16;
    int n    = pixbase + m;
    int b    = n >> 12;
    int y    = (n >> 6) & 63;
    int xc   = n & 63;

    // prologue: 36 A-frag indices (OOB -> basis(0) slot)
    int off[KC_];
#pragma unroll
    for (int kc = 0; kc < KC_; ++kc) {
        int d  = kc * 4 + hi;
        int c  = (d * 57) >> 9;          // d/9
        int r9 = d - c * 9;
        int kh = (r9 * 11) >> 5;         // r9/3
        int kw = r9 - kh * 3;
        int iy = y + kh - 1;
        int ix = xc + kw - 1;
        bool valid = ((unsigned)iy < 64u) & ((unsigned)ix < 64u);
        int pix = ((b * 16 + c) << 12) + (iy << 6) + ix;
        off[kc] = valid ? pix : XB_CONST;
    }
    __syncthreads();                     // B staged

    f32x4 acc0 = {0.f, 0.f, 0.f, 0.f};
    f32x4 acc1 = {0.f, 0.f, 0.f, 0.f};

#pragma unroll
    for (int kc = 0; kc < KC_; ++kc) {
        uint4 au = Xb[off[kc]];
        short8v afrag = __builtin_bit_cast(short8v, au);
        short8v b0 = __builtin_bit_cast(short8v, Bsh[(kc * 2 + 0) * 64 + l]);
        short8v b1 = __builtin_bit_cast(short8v, Bsh[(kc * 2 + 1) * 64 + l]);
        acc0 = __builtin_amdgcn_mfma_f32_16x16x32_bf16(afrag, b0, acc0, 0, 0, 0);
        acc1 = __builtin_amdgcn_mfma_f32_16x16x32_bf16(afrag, b1, acc1, 0, 0, 0);
    }

    // store raw GEMM result
    int prp = (pixbase & 4095) + hi * 4;
    float* dst0 = out + (((size_t)(b * O_ + m)) << 12) + prp;
    float* dst1 = out + (((size_t)(b * O_ + m + 16)) << 12) + prp;
    *reinterpret_cast<f32x4*>(dst0) = acc0;
    *reinterpret_cast<f32x4*>(dst1) = acc1;

    // BN partials from registers
    float s0 = acc0.x + acc0.y + acc0.z + acc0.w;
    float q0 = acc0.x*acc0.x + acc0.y*acc0.y + acc0.z*acc0.z + acc0.w*acc0.w;
    float s1 = acc1.x + acc1.y + acc1.z + acc1.w;
    float q1 = acc1.x*acc1.x + acc1.y*acc1.y + acc1.z*acc1.z + acc1.w*acc1.w;
    s0 += __shfl_xor(s0, 16); s0 += __shfl_xor(s0, 32);
    q0 += __shfl_xor(q0, 16); q0 += __shfl_xor(q0, 32);
    s1 += __shfl_xor(s1, 16); s1 += __shfl_xor(s1, 32);
    q1 += __shfl_xor(q1, 16); q1 += __shfl_xor(q1, 32);

    float* red = (float*)Bsh;
    __syncthreads();                     // done reading Bsh
    if (l < 16) {
        red[wv * 64 +      m] = s0;
        red[wv * 64 + 16 + m] = s1;
        red[wv * 64 + 32 + m] = q0;
        red[wv * 64 + 48 + m] = q1;
    }
    __syncthreads();
    if (tid < 64) {
        float v = 0.f;
#pragma unroll
        for (int w = 0; w < 4; ++w) v += red[w * 64 + tid];
        part[blockIdx.x * 64 + tid] = v;
    }
}

// ---------- BN apply: block bid owns plane bid; o = bid&31 uniform ----------
__global__ void __launch_bounds__(256)
bn_apply(float* __restrict__ out, const float* __restrict__ part,
         const float* __restrict__ gamma, const float* __restrict__ beta) {
    __shared__ float red[256 + 64];
    int tid = threadIdx.x;
    int ch  = tid & 63, grp = tid >> 6;
    float a = 0.f;
#pragma unroll 8
    for (int i = 0; i < 128; ++i)
        a += part[(grp * 128 + i) * 64 + ch];
    red[grp * 64 + ch] = a;
    __syncthreads();
    if (tid < 64)
        red[256 + tid] = red[tid] + red[64 + tid] + red[128 + tid] + red[192 + tid];
    __syncthreads();

    int o = blockIdx.x & 31;
    float S = red[256 + o], Q = red[256 + 32 + o];
    float mean = S * (1.f / (float)NPIX_);
    float var  = Q * (1.f / (float)NPIX_) - mean * mean;
    float rstd = rsqrtf(var + 1e-5f);
    float sc   = gamma[o] * rstd;
    float sh   = beta[o] - mean * sc;

    float4* f4 = reinterpret_cast<float4*>(out) + (size_t)blockIdx.x * 1024;
#pragma unroll
    for (int j = 0; j < 4; ++j) {
        float4 v = f4[tid + j * 256];
        v.x = v.x * sc + sh; v.y = v.y * sc + sh;
        v.z = v.z * sc + sh; v.w = v.w * sc + sh;
        f4[tid + j * 256] = v;
    }
}

extern "C" void kernel_launch(void* const* d_in, const int* in_sizes, int n_in,
                              void* d_out, int out_size, void* d_ws, size_t ws_size,
                              hipStream_t stream) {
    const float* x     = (const float*)d_in[0];
    const float* W     = (const float*)d_in[1];
    const float* gamma = (const float*)d_in[2];
    const float* beta  = (const float*)d_in[3];
    float* out = (float*)d_out;
    unsigned short* Bpack = (unsigned short*)d_ws;
    float* part = (float*)((char*)d_ws + PART_OFF);
    uint4* Xb   = (uint4*)((char*)d_ws + XB_OFF);

    hipLaunchKernelGGL(prep_kernel, dim3(288 + 2048), dim3(256), 0, stream,
                       W, x, Bpack, Xb);
    hipLaunchKernelGGL(main_kernel, dim3(NMAIN_), dim3(256), 0, stream,
                       Xb, (const uint4*)Bpack, out, part);
    hipLaunchKernelGGL(bn_apply, dim3(256), dim3(256), 0, stream,
                       out, part, gamma, beta);
}